// Round 3
// baseline (274.102 us; speedup 1.0000x reference)
//
#include <hip/hip_runtime.h>
#include <hip/hip_bf16.h>

typedef __attribute__((ext_vector_type(8))) short short8;
typedef __attribute__((ext_vector_type(4))) float f32x4;

static constexpr int N = 4096;
static constexpr int D = 1024;
#define TEMP_INV 20.0f

#define GLD_LDS16(gp, lp) __builtin_amdgcn_global_load_lds(                      \
    (const __attribute__((address_space(1))) void*)(gp),                         \
    (__attribute__((address_space(3))) void*)(lp), 16, 0, 0)

// ---------------------------------------------------------------------------
// Kernel 1: row-normalize c and ch -> bf16 workspace; zero the loss slot.
// One block (256 thr) per row; each thread handles one float4 (1024 = 256*4).
// ---------------------------------------------------------------------------
__global__ __launch_bounds__(256) void normalize_k(
    const float* __restrict__ c, const float* __restrict__ ch,
    unsigned short* __restrict__ cnb, unsigned short* __restrict__ chnb,
    float* __restrict__ loss_slot) {
  const int r = blockIdx.x;   // 0..2N-1
  const int t = threadIdx.x;  // 0..255
  if (r == 0 && t == 0) *loss_slot = 0.0f;

  const float* src = (r < N) ? (c + (size_t)r * D) : (ch + (size_t)(r - N) * D);
  unsigned short* dst = (r < N) ? (cnb + (size_t)r * D) : (chnb + (size_t)(r - N) * D);

  float4 v = ((const float4*)src)[t];
  float ss = v.x * v.x + v.y * v.y + v.z * v.z + v.w * v.w;
  #pragma unroll
  for (int off = 32; off > 0; off >>= 1) ss += __shfl_xor(ss, off);
  __shared__ float red[4];
  if ((t & 63) == 0) red[t >> 6] = ss;
  __syncthreads();
  float tot = red[0] + red[1] + red[2] + red[3];
  float sc = 1.0f / fmaxf(sqrtf(tot), 1e-8f);

  __hip_bfloat16 b0 = __float2bfloat16(v.x * sc);
  __hip_bfloat16 b1 = __float2bfloat16(v.y * sc);
  __hip_bfloat16 b2 = __float2bfloat16(v.z * sc);
  __hip_bfloat16 b3 = __float2bfloat16(v.w * sc);
  ushort4 o;
  o.x = *(unsigned short*)&b0;
  o.y = *(unsigned short*)&b1;
  o.z = *(unsigned short*)&b2;
  o.w = *(unsigned short*)&b3;
  ((ushort4*)dst)[t] = o;
}

// ---------------------------------------------------------------------------
// Kernel 2: NT bf16 MFMA GEMM, 128x128 tile, BK=32, 4 waves (2x2 of 64x64).
// sim[i][j] = dot(cn_i, chn_j)  (this IS output 0 = sim*TEMP)
// Also writes y_true[i][j] = (label_i == label_j) as float 0/1.
// ---------------------------------------------------------------------------
__global__ __launch_bounds__(256) void gemm_k(
    const unsigned short* __restrict__ A,  // cn  bf16 [N][D]
    const unsigned short* __restrict__ B,  // chn bf16 [N][D]
    const int* __restrict__ lbl,
    float* __restrict__ sim, float* __restrict__ ytrue) {
  __shared__ __align__(16) unsigned short Als[128 * 32];
  __shared__ __align__(16) unsigned short Bls[128 * 32];

  const int t = threadIdx.x;
  const int w = t >> 6, l = t & 63;
  const int bm = blockIdx.y, bn = blockIdx.x;
  const int wm = w >> 1, wn = w & 1;

  f32x4 acc[4][4] = {};

  // staging: flat chunk idx = p*256 + t covers bytes [idx*16, idx*16+16) of the
  // 8 KB tile; row = idx>>2 (64 B/row), col elem = (idx&3)*8.
  const unsigned short* ga0 = A + (size_t)(bm * 128 + (t >> 2)) * D + (t & 3) * 8;
  const unsigned short* gb0 = B + (size_t)(bn * 128 + (t >> 2)) * D + (t & 3) * 8;
  // wave-uniform LDS bases (HW adds lane*16 bytes)
  unsigned short* la0 = &Als[w * 512];
  unsigned short* la1 = &Als[2048 + w * 512];
  unsigned short* lb0 = &Bls[w * 512];
  unsigned short* lb1 = &Bls[2048 + w * 512];

  const int frow = (l & 15);        // fragment row/col index
  const int fk = (l >> 4) * 8;      // k-chunk for this lane

  for (int k0 = 0; k0 < D; k0 += 32) {
    GLD_LDS16(ga0 + k0, la0);
    GLD_LDS16(ga0 + 64 * D + k0, la1);
    GLD_LDS16(gb0 + k0, lb0);
    GLD_LDS16(gb0 + 64 * D + k0, lb1);
    __syncthreads();  // compiler drains vmcnt before s_barrier

    short8 af[4], bf[4];
    #pragma unroll
    for (int m = 0; m < 4; ++m)
      af[m] = *(const short8*)&Als[(wm * 64 + m * 16 + frow) * 32 + fk];
    #pragma unroll
    for (int n = 0; n < 4; ++n)
      bf[n] = *(const short8*)&Bls[(wn * 64 + n * 16 + frow) * 32 + fk];

    #pragma unroll
    for (int m = 0; m < 4; ++m)
      #pragma unroll
      for (int n = 0; n < 4; ++n)
        acc[m][n] = __builtin_amdgcn_mfma_f32_16x16x32_bf16(af[m], bf[n], acc[m][n], 0, 0, 0);

    __syncthreads();  // before overwriting LDS next iter
  }

  // epilogue: C/D mapping col = lane&15, row = (lane>>4)*4 + reg
  const int row0 = bm * 128 + wm * 64;
  const int col0 = bn * 128 + wn * 64;
  int lc[4];
  #pragma unroll
  for (int n = 0; n < 4; ++n) lc[n] = lbl[col0 + n * 16 + (l & 15)];

  #pragma unroll
  for (int m = 0; m < 4; ++m) {
    #pragma unroll
    for (int r = 0; r < 4; ++r) {
      const int grow = row0 + m * 16 + (l >> 4) * 4 + r;
      const int lr = lbl[grow];
      const size_t base = (size_t)grow * N + col0 + (l & 15);
      #pragma unroll
      for (int n = 0; n < 4; ++n) {
        sim[base + n * 16] = acc[m][n][r];
        ytrue[base + n * 16] = (lr == lc[n]) ? 1.0f : 0.0f;
      }
    }
  }
}

// ---------------------------------------------------------------------------
// Kernel 3: per-row SupCon reduction. One block per row; row staged in LDS.
// row_val = 20*psum/cnt - 20*M - log(sum_j exp(20*(x_j - M)))
// loss += -row_val / N   (atomic, one per row)
// ---------------------------------------------------------------------------
__global__ __launch_bounds__(256) void row_loss_k(
    const float* __restrict__ sim, const int* __restrict__ lbl,
    float* loss_slot) {
  const int i = blockIdx.x, t = threadIdx.x;
  __shared__ __align__(16) float buf[N];
  __shared__ float redm[4], reds[4], redp[4], redc[4];

  const float4* rp = (const float4*)(sim + (size_t)i * N);
  float4* bp = (float4*)buf;
  float mmax = -3.402823e38f;
  #pragma unroll
  for (int q = 0; q < 4; ++q) {
    float4 x = rp[t + q * 256];
    bp[t + q * 256] = x;
    mmax = fmaxf(fmaxf(mmax, fmaxf(x.x, x.y)), fmaxf(x.z, x.w));
  }
  #pragma unroll
  for (int off = 32; off > 0; off >>= 1) mmax = fmaxf(mmax, __shfl_xor(mmax, off));
  if ((t & 63) == 0) redm[t >> 6] = mmax;
  __syncthreads();
  const float M = fmaxf(fmaxf(redm[0], redm[1]), fmaxf(redm[2], redm[3]));

  const int li = lbl[i];
  float sexp = 0.f, psum = 0.f, cnt = 0.f;
  for (int j = t; j < N; j += 256) {
    float x = buf[j];
    sexp += expf((x - M) * TEMP_INV);
    if (lbl[j] == li) { psum += x; cnt += 1.0f; }
  }
  #pragma unroll
  for (int off = 32; off > 0; off >>= 1) {
    sexp += __shfl_xor(sexp, off);
    psum += __shfl_xor(psum, off);
    cnt  += __shfl_xor(cnt, off);
  }
  if ((t & 63) == 0) { reds[t >> 6] = sexp; redp[t >> 6] = psum; redc[t >> 6] = cnt; }
  __syncthreads();
  if (t == 0) {
    sexp = reds[0] + reds[1] + reds[2] + reds[3];
    psum = redp[0] + redp[1] + redp[2] + redp[3];
    cnt  = redc[0] + redc[1] + redc[2] + redc[3];
    float row = psum * TEMP_INV / cnt - M * TEMP_INV - logf(sexp);
    atomicAdd(loss_slot, -row * (1.0f / (float)N));
  }
}

// ---------------------------------------------------------------------------
extern "C" void kernel_launch(void* const* d_in, const int* in_sizes, int n_in,
                              void* d_out, int out_size, void* d_ws, size_t ws_size,
                              hipStream_t stream) {
  const float* c  = (const float*)d_in[0];
  const float* ch = (const float*)d_in[1];
  const int* lbl  = (const int*)d_in[2];

  float* out = (float*)d_out;
  float* sim = out;                            // [N*N]
  float* loss_slot = out + (size_t)N * N;      // [1]
  float* ytrue = out + (size_t)N * N + 1;      // [N*N]

  unsigned short* cnb  = (unsigned short*)d_ws;          // bf16 cn  [N][D]
  unsigned short* chnb = cnb + (size_t)N * D;            // bf16 chn [N][D]

  normalize_k<<<2 * N, 256, 0, stream>>>(c, ch, cnb, chnb, loss_slot);
  dim3 g(N / 128, N / 128);
  gemm_k<<<g, 256, 0, stream>>>(cnb, chnb, lbl, sim, ytrue);
  row_loss_k<<<N, 256, 0, stream>>>(sim, lbl, loss_slot);
}

// Round 5
// 222.735 us; speedup vs baseline: 1.2306x; 1.2306x over previous
//
#include <hip/hip_runtime.h>
#include <hip/hip_bf16.h>

typedef __attribute__((ext_vector_type(8))) short short8;
typedef __attribute__((ext_vector_type(4))) float f32x4;

static constexpr int N = 4096;
static constexpr int D = 1024;
#define TEMP_INV 20.0f
#define LOG2E_X20 28.8539008178f   // 20 * log2(e); exp(20x) == exp2(x * this)

#define GLD_LDS16(gp, lp) __builtin_amdgcn_global_load_lds(                      \
    (const __attribute__((address_space(1))) void*)(gp),                         \
    (__attribute__((address_space(3))) void*)(lp), 16, 0, 0)

// ---------------------------------------------------------------------------
// Kernel 1: row-normalize c and ch -> bf16 workspace; zero the loss slot.
// ---------------------------------------------------------------------------
__global__ __launch_bounds__(256) void normalize_k(
    const float* __restrict__ c, const float* __restrict__ ch,
    unsigned short* __restrict__ cnb, unsigned short* __restrict__ chnb,
    float* __restrict__ loss_slot) {
  const int r = blockIdx.x;   // 0..2N-1
  const int t = threadIdx.x;  // 0..255
  if (r == 0 && t == 0) *loss_slot = 0.0f;

  const float* src = (r < N) ? (c + (size_t)r * D) : (ch + (size_t)(r - N) * D);
  unsigned short* dst = (r < N) ? (cnb + (size_t)r * D) : (chnb + (size_t)(r - N) * D);

  float4 v = ((const float4*)src)[t];
  float ss = v.x * v.x + v.y * v.y + v.z * v.z + v.w * v.w;
  #pragma unroll
  for (int off = 32; off > 0; off >>= 1) ss += __shfl_xor(ss, off);
  __shared__ float red[4];
  if ((t & 63) == 0) red[t >> 6] = ss;
  __syncthreads();
  float tot = red[0] + red[1] + red[2] + red[3];
  float sc = 1.0f / fmaxf(sqrtf(tot), 1e-8f);

  __hip_bfloat16 b0 = __float2bfloat16(v.x * sc);
  __hip_bfloat16 b1 = __float2bfloat16(v.y * sc);
  __hip_bfloat16 b2 = __float2bfloat16(v.z * sc);
  __hip_bfloat16 b3 = __float2bfloat16(v.w * sc);
  ushort4 o;
  o.x = *(unsigned short*)&b0;
  o.y = *(unsigned short*)&b1;
  o.z = *(unsigned short*)&b2;
  o.w = *(unsigned short*)&b3;
  ((ushort4*)dst)[t] = o;
}

// ---------------------------------------------------------------------------
// Kernel 2: y_true[i][j] = (label_i == label_j).
// NOTE: yt = out + N*N + 1 is only 4-byte aligned -> scalar dword stores
// ONLY (dwordx4 would fault). Each wave store still covers 256 contiguous
// bytes, so write coalescing matches float4.
// Block b covers flat elements [b*1024, b*1024+1024); thread t does 4
// elements at t, t+256, t+512, t+768 within that window.
// ---------------------------------------------------------------------------
__global__ __launch_bounds__(256) void ytrue_k(
    const int* __restrict__ lbl, float* __restrict__ yt) {
  const size_t base = (size_t)blockIdx.x * 1024;
  const int row = (int)(base >> 12);           // 4096 elements per row
  const int lr = lbl[row];                     // one row per 4 blocks (4096/1024)
  #pragma unroll
  for (int q = 0; q < 4; ++q) {
    const size_t e = base + q * 256 + threadIdx.x;
    const int col = (int)(e & 4095);
    yt[e] = (lbl[col] == lr) ? 1.0f : 0.0f;
  }
}

// ---------------------------------------------------------------------------
// Kernel 3: NT bf16 MFMA GEMM, 128x128 tile, BK=32, 4 waves (2x2 of 64x64).
// Writes sim and per-wave per-row loss partials:
//   part[row][tile] = { s = sum_cols exp(20*v),  p = sum_cols mask*v }
// tile = bn*2 + wn (64 col-chunks of 64). No max subtraction needed: |v|<=1.
// ---------------------------------------------------------------------------
__global__ __launch_bounds__(256) void gemm_k(
    const unsigned short* __restrict__ A,  // cn  bf16 [N][D]
    const unsigned short* __restrict__ B,  // chn bf16 [N][D]
    const int* __restrict__ lbl,
    float* __restrict__ sim, float* __restrict__ part) {
  __shared__ __align__(16) unsigned short Als[128 * 32];
  __shared__ __align__(16) unsigned short Bls[128 * 32];

  const int t = threadIdx.x;
  const int w = t >> 6, l = t & 63;
  const int bm = blockIdx.y, bn = blockIdx.x;
  const int wm = w >> 1, wn = w & 1;

  f32x4 acc[4][4] = {};

  const unsigned short* ga0 = A + (size_t)(bm * 128 + (t >> 2)) * D + (t & 3) * 8;
  const unsigned short* gb0 = B + (size_t)(bn * 128 + (t >> 2)) * D + (t & 3) * 8;
  unsigned short* la0 = &Als[w * 512];
  unsigned short* la1 = &Als[2048 + w * 512];
  unsigned short* lb0 = &Bls[w * 512];
  unsigned short* lb1 = &Bls[2048 + w * 512];

  const int frow = (l & 15);
  const int fk = (l >> 4) * 8;

  for (int k0 = 0; k0 < D; k0 += 32) {
    GLD_LDS16(ga0 + k0, la0);
    GLD_LDS16(ga0 + 64 * D + k0, la1);
    GLD_LDS16(gb0 + k0, lb0);
    GLD_LDS16(gb0 + 64 * D + k0, lb1);
    __syncthreads();

    short8 af[4], bf[4];
    #pragma unroll
    for (int m = 0; m < 4; ++m)
      af[m] = *(const short8*)&Als[(wm * 64 + m * 16 + frow) * 32 + fk];
    #pragma unroll
    for (int n = 0; n < 4; ++n)
      bf[n] = *(const short8*)&Bls[(wn * 64 + n * 16 + frow) * 32 + fk];

    #pragma unroll
    for (int m = 0; m < 4; ++m)
      #pragma unroll
      for (int n = 0; n < 4; ++n)
        acc[m][n] = __builtin_amdgcn_mfma_f32_16x16x32_bf16(af[m], bf[n], acc[m][n], 0, 0, 0);

    __syncthreads();
  }

  // Epilogue. C/D mapping: col = lane&15, row = (lane>>4)*4 + reg.
  // For a fixed (m,r): the 16 lanes sharing (l>>4) hold the same row,
  // cols col0 + n*16 + (l&15) -> shfl_xor {1,2,4,8} row-reduces.
  const int row0 = bm * 128 + wm * 64;
  const int col0 = bn * 128 + wn * 64;
  const int tile = bn * 2 + wn;
  int lc[4];
  #pragma unroll
  for (int n = 0; n < 4; ++n) lc[n] = lbl[col0 + n * 16 + (l & 15)];

  #pragma unroll
  for (int m = 0; m < 4; ++m) {
    #pragma unroll
    for (int r = 0; r < 4; ++r) {
      const int grow = row0 + m * 16 + (l >> 4) * 4 + r;
      const int lr = lbl[grow];
      const size_t base = (size_t)grow * N + col0 + (l & 15);
      float s = 0.0f, p = 0.0f;
      #pragma unroll
      for (int n = 0; n < 4; ++n) {
        const float v = acc[m][n][r];
        sim[base + n * 16] = v;
        s += exp2f(v * LOG2E_X20);
        p += (lc[n] == lr) ? v : 0.0f;
      }
      #pragma unroll
      for (int off = 1; off < 16; off <<= 1) {
        s += __shfl_xor(s, off);
        p += __shfl_xor(p, off);
      }
      if ((l & 15) == 0) {
        float* pp = &part[(size_t)grow * 128 + tile * 2];
        pp[0] = s;
        pp[1] = p;
      }
    }
  }
}

// ---------------------------------------------------------------------------
// Kernel 4: finalize. 16 blocks x 256 thr; thread t of block b owns row i.
// cnt from a label histogram; sexp/psum from 64 tile partials.
// row_val = 20*psum/cnt - log(sexp); loss = mean(-row_val).
// ---------------------------------------------------------------------------
__global__ __launch_bounds__(256) void finalize_k(
    const float* __restrict__ part, const int* __restrict__ lbl,
    float* loss_slot) {
  __shared__ int hist[64];
  __shared__ float redl[4];
  const int t = threadIdx.x;
  const int i = blockIdx.x * 256 + t;

  if (t < 64) hist[t] = 0;
  __syncthreads();
  for (int j = t; j < N; j += 256) atomicAdd(&hist[lbl[j] & 63], 1);
  __syncthreads();

  const float* pr = part + (size_t)i * 128;
  float sexp = 0.0f, psum = 0.0f;
  #pragma unroll
  for (int tt = 0; tt < 64; ++tt) {
    sexp += pr[tt * 2];
    psum += pr[tt * 2 + 1];
  }
  const float cnt = (float)hist[lbl[i] & 63];
  const float row = TEMP_INV * psum / cnt - logf(sexp);
  float contrib = -row * (1.0f / (float)N);

  #pragma unroll
  for (int off = 32; off > 0; off >>= 1) contrib += __shfl_xor(contrib, off);
  if ((t & 63) == 0) redl[t >> 6] = contrib;
  __syncthreads();
  if (t == 0) atomicAdd(loss_slot, redl[0] + redl[1] + redl[2] + redl[3]);
}

// ---------------------------------------------------------------------------
extern "C" void kernel_launch(void* const* d_in, const int* in_sizes, int n_in,
                              void* d_out, int out_size, void* d_ws, size_t ws_size,
                              hipStream_t stream) {
  const float* c  = (const float*)d_in[0];
  const float* ch = (const float*)d_in[1];
  const int* lbl  = (const int*)d_in[2];

  float* out = (float*)d_out;
  float* sim = out;                            // [N*N]
  float* loss_slot = out + (size_t)N * N;      // [1]
  float* ytrue = out + (size_t)N * N + 1;      // [N*N] (only 4B-aligned!)

  unsigned short* cnb  = (unsigned short*)d_ws;            // bf16 cn  [N][D]
  unsigned short* chnb = cnb + (size_t)N * D;              // bf16 chn [N][D]
  float* part = (float*)(chnb + (size_t)N * D);            // [N][64][2] = 2 MB

  normalize_k<<<2 * N, 256, 0, stream>>>(c, ch, cnb, chnb, loss_slot);
  ytrue_k<<<N * N / 1024, 256, 0, stream>>>(lbl, ytrue);
  dim3 g(N / 128, N / 128);
  gemm_k<<<g, 256, 0, stream>>>(cnb, chnb, lbl, sim, part);
  finalize_k<<<N / 256, 256, 0, stream>>>(part, lbl, loss_slot);
}